// Round 5
// baseline (205.692 us; speedup 1.0000x reference)
//
#include <hip/hip_runtime.h>
#include <hip/hip_bf16.h>

#define BB 8
#define SS 512
#define HIDV 768
#define HH 12
#define DD 64
#define LV 81

typedef __attribute__((ext_vector_type(8))) short short8v;
typedef __attribute__((ext_vector_type(4))) short short4v;
typedef __attribute__((ext_vector_type(4))) float f32x4;

#define MFMA16(a, b, c) __builtin_amdgcn_mfma_f32_16x16x32_bf16(a, b, c, 0, 0, 0)

__device__ __forceinline__ short f2bf(float f) {
    __hip_bfloat16 h = __float2bfloat16(f);
    return *reinterpret_cast<short*>(&h);
}
__device__ __forceinline__ float bf2f(short s) {
    __hip_bfloat16 h = *reinterpret_cast<__hip_bfloat16*>(&s);
    return __bfloat162float(h);
}
__device__ __forceinline__ void gload16(const void* g, void* l) {
    __builtin_amdgcn_global_load_lds((const __attribute__((address_space(1))) void*)g,
                                     (__attribute__((address_space(3))) void*)l, 16, 0, 0);
}

// ---------------- Kernel A: LN tables -> lnkb bf16 [96][64], lnvT bf16 [64][96] ----------------
__global__ __launch_bounds__(256) void prep_ln_kernel(
    const float* __restrict__ rel_k, const float* __restrict__ rel_v,
    const float* __restrict__ gk, const float* __restrict__ bk,
    const float* __restrict__ gv, const float* __restrict__ bv,
    short* __restrict__ lnkb, short* __restrict__ lnvT) {
    __shared__ float ln_lds[2 * LV][DD];
    int t = threadIdx.x;
    if (t < 2 * LV) {
        bool isv = (t >= LV);
        int r = isv ? t - LV : t;
        const float* row = (isv ? rel_v : rel_k) + r * DD;
        const float* g = isv ? gv : gk;
        const float* be = isv ? bv : bk;
        float mu = 0.f;
        for (int d = 0; d < DD; ++d) mu += row[d];
        mu *= (1.f / DD);
        float var = 0.f;
        for (int d = 0; d < DD; ++d) { float x = row[d] - mu; var += x * x; }
        var *= (1.f / DD);
        float rs = rsqrtf(var + 1e-5f);
        for (int d = 0; d < DD; ++d) ln_lds[t][d] = (row[d] - mu) * rs * g[d] + be[d];
    }
    __syncthreads();
    for (int i = t; i < 96 * DD; i += 256) {
        int l = i >> 6, d = i & 63;
        lnkb[i] = (l < LV) ? f2bf(ln_lds[l][d]) : (short)0;
    }
    for (int i = t; i < DD * 96; i += 256) {
        int d = i / 96, ll = i - d * 96;
        lnvT[i] = (ll < LV) ? f2bf(ln_lds[LV + ll][d]) : (short)0;
    }
}

// ---------------- hidden f32 -> bf16 ----------------
__global__ __launch_bounds__(256) void conv_hidden_kernel(const float* __restrict__ in,
                                                          short* __restrict__ out) {
    int i = (blockIdx.x * 256 + threadIdx.x) * 4;
    float4 v = *reinterpret_cast<const float4*>(&in[i]);
    short4v o; o[0] = f2bf(v.x); o[1] = f2bf(v.y); o[2] = f2bf(v.z); o[3] = f2bf(v.w);
    *reinterpret_cast<short4v*>(&out[i]) = o;
}

// ---------------- W [k][n] f32 -> WT [n][k] bf16 (x3 via z) ----------------
__global__ __launch_bounds__(256) void transw_kernel(
    const float* __restrict__ Wq, const float* __restrict__ Wk, const float* __restrict__ Wv,
    short* __restrict__ WqT, short* __restrict__ WkT, short* __restrict__ WvT) {
    const float* W; short* O;
    if (blockIdx.z == 0) { W = Wq; O = WqT; }
    else if (blockIdx.z == 1) { W = Wk; O = WkT; }
    else { W = Wv; O = WvT; }
    __shared__ float tile[32][33];
    int k0 = blockIdx.y * 32, n0 = blockIdx.x * 32;
    int t = threadIdx.x;
    int r = t >> 3, c4 = (t & 7) * 4;
    float4 v = *reinterpret_cast<const float4*>(&W[(size_t)(k0 + r) * HIDV + n0 + c4]);
    tile[r][c4 + 0] = v.x; tile[r][c4 + 1] = v.y; tile[r][c4 + 2] = v.z; tile[r][c4 + 3] = v.w;
    __syncthreads();
    short4v o;
    o[0] = f2bf(tile[c4 + 0][r]); o[1] = f2bf(tile[c4 + 1][r]);
    o[2] = f2bf(tile[c4 + 2][r]); o[3] = f2bf(tile[c4 + 3][r]);
    *reinterpret_cast<short4v*>(&O[(size_t)(n0 + r) * HIDV + k0 + c4]) = o;
}

// ---------------- arc int32 [b][q][k] -> uint8 transposed arcT [b][k][q] ----------------
__global__ __launch_bounds__(256) void arct_kernel(const int* __restrict__ arc,
                                                   unsigned char* __restrict__ arcT) {
    __shared__ unsigned char t8[64][68];
    const int tid = threadIdx.x;
    const int bz = blockIdx.z;
    const int q0 = blockIdx.y * 64, k0 = blockIdx.x * 64;
    for (int i = tid; i < 64 * 16; i += 256) {
        int r = i >> 4, c4 = (i & 15) * 4;
        int4 v = *reinterpret_cast<const int4*>(&arc[((size_t)(bz * SS) + q0 + r) * SS + k0 + c4]);
        t8[c4 + 0][r] = (unsigned char)v.x;
        t8[c4 + 1][r] = (unsigned char)v.y;
        t8[c4 + 2][r] = (unsigned char)v.z;
        t8[c4 + 3][r] = (unsigned char)v.w;
    }
    __syncthreads();
    for (int i = tid; i < 64 * 16; i += 256) {
        int c = i >> 4, r4 = (i & 15) * 4;
        unsigned int vv = *reinterpret_cast<const unsigned int*>(&t8[c][r4]);
        *reinterpret_cast<unsigned int*>(&arcT[((size_t)(bz * SS) + k0 + c) * SS + q0 + r4]) = vv;
    }
}

// ---------------- QKV GEMM bf16 MFMA (unchanged) ----------------
__global__ __launch_bounds__(256) void qkv_gemm_kernel(
    const short* __restrict__ Abf,
    const short* __restrict__ WqT, const short* __restrict__ WkT, const short* __restrict__ WvT,
    const float* __restrict__ bq, const float* __restrict__ bk, const float* __restrict__ bv,
    short* __restrict__ qo, short* __restrict__ ko, short* __restrict__ vto) {
    const short* Bt; const float* bias;
    int z = blockIdx.z;
    if (z == 0) { Bt = WqT; bias = bq; }
    else if (z == 1) { Bt = WkT; bias = bk; }
    else { Bt = WvT; bias = bv; }

    __shared__ short smem[8192];
    short* As = smem;
    short* Bs = smem + 4096;

    const int tid = threadIdx.x;
    const int lane = tid & 63, w = tid >> 6;
    const int li = lane & 15, g = lane >> 4;
    const int wr = w >> 1, wc = w & 1;
    const int m0 = blockIdx.y * 64, n0 = blockIdx.x * 64;

    f32x4 acc[2][2];
    for (int ra = 0; ra < 2; ++ra)
        for (int cb = 0; cb < 2; ++cb)
            for (int r = 0; r < 4; ++r) acc[ra][cb][r] = 0.f;

#pragma unroll 1
    for (int k0 = 0; k0 < HIDV; k0 += 64) {
#pragma unroll
        for (int j = 0; j < 2; ++j) {
            int c = j * 256 + tid;
            int row = c >> 3, s = c & 7;
            int src = s ^ (row & 7);
            gload16(Abf + (size_t)(m0 + row) * HIDV + k0 + src * 8, As + c * 8);
            gload16(Bt + (size_t)(n0 + row) * HIDV + k0 + src * 8, Bs + c * 8);
        }
        __syncthreads();
#pragma unroll
        for (int c = 0; c < 2; ++c) {
            short8v af[2], bf[2];
#pragma unroll
            for (int ra = 0; ra < 2; ++ra) {
                int row = 32 * wr + 16 * ra + li;
                int chunk = (4 * c + g) ^ (row & 7);
                af[ra] = *reinterpret_cast<const short8v*>(&As[row * 64 + chunk * 8]);
            }
#pragma unroll
            for (int cb = 0; cb < 2; ++cb) {
                int rowb = 32 * wc + 16 * cb + li;
                int chunk = (4 * c + g) ^ (rowb & 7);
                bf[cb] = *reinterpret_cast<const short8v*>(&Bs[rowb * 64 + chunk * 8]);
            }
#pragma unroll
            for (int ra = 0; ra < 2; ++ra)
#pragma unroll
                for (int cb = 0; cb < 2; ++cb)
                    acc[ra][cb] = MFMA16(af[ra], bf[cb], acc[ra][cb]);
        }
        __syncthreads();
    }

    const int h = n0 >> 6;
    const int bidx = m0 >> 9;
    if (z < 2) {
        short* dst = (z == 0) ? qo : ko;
        float sc = (z == 0) ? 1.f : 0.125f;
#pragma unroll
        for (int ra = 0; ra < 2; ++ra)
#pragma unroll
            for (int cb = 0; cb < 2; ++cb) {
                int n = 32 * wc + 16 * cb + li;
                float bv_ = bias[n0 + n];
#pragma unroll
                for (int r = 0; r < 4; ++r) {
                    int m = m0 + 32 * wr + 16 * ra + 4 * g + r;
                    int s = m & 511;
                    dst[(((size_t)bidx * HH + h) * SS + s) * DD + n] =
                        f2bf((acc[ra][cb][r] + bv_) * sc);
                }
            }
    } else {
        short* Cs = smem;
#pragma unroll
        for (int ra = 0; ra < 2; ++ra)
#pragma unroll
            for (int cb = 0; cb < 2; ++cb) {
                int nl = 32 * wc + 16 * cb + li;
                float bv_ = bias[n0 + nl];
#pragma unroll
                for (int r = 0; r < 4; ++r) {
                    int ml = 32 * wr + 16 * ra + 4 * g + r;
                    Cs[nl * 72 + ml] = f2bf(acc[ra][cb][r] + bv_);
                }
            }
        __syncthreads();
        for (int c = tid; c < 512; c += 256) {
            int dl = c >> 3, s8 = (c & 7) * 8;
            short8v vv = *reinterpret_cast<const short8v*>(&Cs[dl * 72 + s8]);
            *reinterpret_cast<short8v*>(
                &vto[(((size_t)bidx * HH + h) * DD + dl) * SS + (m0 & 511) + s8]) = vv;
        }
    }
}

// ---------------- fused MFMA attention: pure staged-VMEM counted pipeline ----------------
// 256 thr = 4 waves, block covers 64 q-rows of one bh. The ONLY in-loop VMEM are
// 5 global_load_lds per thread per iter (A1 | V2 | K2), order pinned; vmcnt(4)/(2)
// keep K(kt+1) in flight across barriers. All loop operands (arc bytes, mask,
// qrel, P, buckets) live in LDS.
__global__ __launch_bounds__(256, 2) void attn_kernel(
    const short* __restrict__ qb, const short* __restrict__ kb, const short* __restrict__ vt,
    const unsigned char* __restrict__ arcT, const float* __restrict__ mask,
    const short* __restrict__ lnkb, const short* __restrict__ lnvT,
    float* __restrict__ outp) {
    __shared__ short Ks[2][64][64];      // 16 KB
    __shared__ short Vs[64][64];         // 8 KB
    __shared__ unsigned char As[4096];   // 4 KB: [k-col][16B chunks of q, chunk^col&3]
    __shared__ short maskL[512];         // 1 KB bf16
    __shared__ float qlds[4][16][81];    // 20.25 KB (wave-private rows)
    __shared__ float bucket[4][16][84];  // 21 KB
    __shared__ short pl[4][16][72];      // 9 KB
    // total 81152 B -> 2 blocks/CU

    const int tid = threadIdx.x;
    const int w = tid >> 6, lane = tid & 63;
    const int li = lane & 15, g = lane >> 4;
    const int bx = blockIdx.x;
    const int b = bx & 7;                 // XCD affinity: batch-major
    const int rest = bx >> 3;
    const int h = rest % HH, qt = rest / HH;
    const int bh = b * HH + h;
    const int q0b = qt * 64;
    const int q0 = q0b + w * 16;

    const short* kbp = kb + (size_t)bh * SS * DD;
    const short* vbp = vt + (size_t)bh * DD * SS;
    const unsigned char* abp = arcT + (size_t)b * SS * SS;

    // ---- prologue ----
#pragma unroll
    for (int j = 0; j < 2; ++j) {                      // stage K(0)
        int c = tid + 256 * j, row = c >> 3, s8 = (c & 7) ^ (row & 7);
        gload16(kbp + (size_t)row * DD + s8 * 8, &Ks[0][0][0] + c * 8);
    }
    for (int i = tid; i < SS; i += 256) maskL[i] = f2bf(mask[b * SS + i]);
    for (int i = lane; i < 16 * 84; i += 64) (&bucket[w][0][0])[i] = 0.f;

    short8v qf[2];
    {
        const short* qrow = qb + ((size_t)bh * SS + q0 + li) * DD + 8 * g;
        qf[0] = *reinterpret_cast<const short8v*>(qrow);
        qf[1] = *reinterpret_cast<const short8v*>(qrow + 32);
    }

    // qrel tile via MFMA: [16 rows][81 labels] (wave-private)
    {
        f32x4 qr[6];
#pragma unroll
        for (int ct = 0; ct < 6; ++ct) {
            f32x4 a = {0.f, 0.f, 0.f, 0.f};
            short8v b0 = *reinterpret_cast<const short8v*>(&lnkb[(16 * ct + li) * DD + 8 * g]);
            short8v b1 = *reinterpret_cast<const short8v*>(&lnkb[(16 * ct + li) * DD + 32 + 8 * g]);
            a = MFMA16(qf[0], b0, a);
            a = MFMA16(qf[1], b1, a);
            qr[ct] = a;
        }
#pragma unroll
        for (int ct = 0; ct < 6; ++ct)
#pragma unroll
            for (int r = 0; r < 4; ++r)
                if (16 * ct + li < 81) qlds[w][4 * g + r][16 * ct + li] = qr[ct][r];
    }
    asm volatile("s_waitcnt lgkmcnt(0)" ::: "memory");  // maskL visible before first barrier

    f32x4 oacc[4];
    for (int t = 0; t < 4; ++t) for (int r = 0; r < 4; ++r) oacc[t][r] = 0.f;
    float lsum[4] = {0.f, 0.f, 0.f, 0.f};

#pragma unroll
    for (int kt = 0; kt < 8; ++kt) {
        const int cur = kt & 1, nxt = cur ^ 1;
        const int kb0 = kt * 64;

        __builtin_amdgcn_sched_barrier(0);
        __builtin_amdgcn_s_barrier();          // prev reads of Vs / Ks[nxt] / As done
        __builtin_amdgcn_sched_barrier(0);

        // issue A(kt)  [oldest of this iter]
        {
            int col = tid >> 2, seg = tid & 3;
            int sc_ = seg ^ (col & 3);
            gload16(abp + (size_t)(kb0 + col) * SS + q0b + sc_ * 16, As + tid * 16);
        }
        __builtin_amdgcn_sched_barrier(0);
        // issue V(kt)
#pragma unroll
        for (int j = 0; j < 2; ++j) {
            int c = tid + 256 * j, row = c >> 3, s8 = (c & 7) ^ (row & 7);
            gload16(vbp + (size_t)row * SS + kb0 + s8 * 8, &Vs[0][0] + c * 8);
        }
        __builtin_amdgcn_sched_barrier(0);
        // issue K(kt+1)
        if (kt < 7) {
#pragma unroll
            for (int j = 0; j < 2; ++j) {
                int c = tid + 256 * j, row = c >> 3, s8 = (c & 7) ^ (row & 7);
                gload16(kbp + (size_t)(kb0 + 64 + row) * DD + s8 * 8, &Ks[nxt][0][0] + c * 8);
            }
            __builtin_amdgcn_sched_barrier(0);
            asm volatile("s_waitcnt vmcnt(4)" ::: "memory");  // K(kt)+A(kt) landed (own)
        } else {
            asm volatile("s_waitcnt vmcnt(2)" ::: "memory");
        }
        __builtin_amdgcn_sched_barrier(0);
        __builtin_amdgcn_s_barrier();          // K(kt)+A(kt) visible block-wide
        __builtin_amdgcn_sched_barrier(0);

        // QK^T from LDS (K pre-scaled by 0.125)
        f32x4 sacc[4];
#pragma unroll
        for (int t = 0; t < 4; ++t) {
            int row = 16 * t + li;
            short8v kf0 = *reinterpret_cast<const short8v*>(&Ks[cur][row][((g) ^ (li & 7)) * 8]);
            short8v kf1 = *reinterpret_cast<const short8v*>(&Ks[cur][row][((4 + g) ^ (li & 7)) * 8]);
            f32x4 a = {0.f, 0.f, 0.f, 0.f};
            a = MFMA16(qf[0], kf0, a);
            a = MFMA16(qf[1], kf1, a);
            sacc[t] = a;
        }

        // exp stage: all-LDS (arc bytes, mask, qrel) + bucket atomic + P write
#pragma unroll
        for (int t = 0; t < 4; ++t) {
            const int col = 16 * t + li;
            const float mval = bf2f(maskL[kb0 + col]);
            unsigned int a4 = *reinterpret_cast<const unsigned int*>(
                &As[col * 64 + (((w ^ (col & 3)) << 4) | (g << 2))]);
#pragma unroll
            for (int r = 0; r < 4; ++r) {
                const int a_ = (a4 >> (8 * r)) & 255;
                const int row = 4 * g + r;
                float s = sacc[t][r] + qlds[w][row][a_] + mval;
                float p = __expf(s);
                lsum[r] += p;
                atomicAdd(&bucket[w][row][a_], p);
                pl[w][row][col] = f2bf(p);
            }
        }

        // V(kt) landed (leaves K(kt+1) in flight)
        if (kt < 7) asm volatile("s_waitcnt vmcnt(2)" ::: "memory");
        else        asm volatile("s_waitcnt vmcnt(0)" ::: "memory");
        __builtin_amdgcn_sched_barrier(0);
        __builtin_amdgcn_s_barrier();          // V visible block-wide
        __builtin_amdgcn_sched_barrier(0);

        // PV from LDS
        short8v pf0 = *reinterpret_cast<const short8v*>(&pl[w][li][8 * g]);
        short8v pf1 = *reinterpret_cast<const short8v*>(&pl[w][li][8 * g + 32]);
#pragma unroll
        for (int t2 = 0; t2 < 4; ++t2) {
            int row = 16 * t2 + li;
            short8v vf0 = *reinterpret_cast<const short8v*>(&Vs[row][((g) ^ (li & 7)) * 8]);
            short8v vf1 = *reinterpret_cast<const short8v*>(&Vs[row][((4 + g) ^ (li & 7)) * 8]);
            oacc[t2] = MFMA16(pf0, vf0, oacc[t2]);
            oacc[t2] = MFMA16(pf1, vf1, oacc[t2]);
        }
    }

    // row sums across the 16-lane group
#pragma unroll
    for (int off = 1; off < 16; off <<= 1)
#pragma unroll
        for (int r = 0; r < 4; ++r) lsum[r] += __shfl_xor(lsum[r], off);

    // rel-V: racc = bucket @ lnvT  (labels 0..80; chunk c=2 guarded)
    f32x4 racc[4];
    for (int t = 0; t < 4; ++t) for (int r = 0; r < 4; ++r) racc[t][r] = 0.f;
#pragma unroll
    for (int c = 0; c < 3; ++c) {
        f32x4 b0, b1;
        if (c < 2) {
            b0 = *reinterpret_cast<const f32x4*>(&bucket[w][li][8 * g + 32 * c]);
            b1 = *reinterpret_cast<const f32x4*>(&bucket[w][li][8 * g + 32 * c + 4]);
        } else {
#pragma unroll
            for (int e = 0; e < 4; ++e) {
                int c0 = 64 + 8 * g + e, c1 = c0 + 4;
                b0[e] = (c0 < 81) ? bucket[w][li][c0] : 0.f;
                b1[e] = (c1 < 81) ? bucket[w][li][c1] : 0.f;
            }
        }
        short8v bfr;
        bfr[0] = f2bf(b0[0]); bfr[1] = f2bf(b0[1]); bfr[2] = f2bf(b0[2]); bfr[3] = f2bf(b0[3]);
        bfr[4] = f2bf(b1[0]); bfr[5] = f2bf(b1[1]); bfr[6] = f2bf(b1[2]); bfr[7] = f2bf(b1[3]);
#pragma unroll
        for (int t2 = 0; t2 < 4; ++t2) {
            short8v lf = *reinterpret_cast<const short8v*>(
                &lnvT[(16 * t2 + li) * 96 + 8 * g + 32 * c]);
            racc[t2] = MFMA16(bfr, lf, racc[t2]);
        }
    }

    float inv[4];
#pragma unroll
    for (int r = 0; r < 4; ++r) inv[r] = 1.f / lsum[r];

#pragma unroll
    for (int t2 = 0; t2 < 4; ++t2)
#pragma unroll
        for (int r = 0; r < 4; ++r) {
            int row = q0 + 4 * g + r;
            outp[((size_t)b * SS + row) * HIDV + h * DD + 16 * t2 + li] =
                (oacc[t2][r] + racc[t2][r]) * inv[r];
        }
}

// ---------------- launcher ----------------
extern "C" void kernel_launch(void* const* d_in, const int* in_sizes, int n_in,
                              void* d_out, int out_size, void* d_ws, size_t ws_size,
                              hipStream_t stream) {
    const float* hidden = (const float*)d_in[0];
    const float* mask   = (const float*)d_in[1];
    const int*   arc    = (const int*)d_in[2];
    const float* Wq = (const float*)d_in[3];
    const float* bq = (const float*)d_in[4];
    const float* Wk = (const float*)d_in[5];
    const float* bk = (const float*)d_in[6];
    const float* Wv = (const float*)d_in[7];
    const float* bv = (const float*)d_in[8];
    const float* rel_k = (const float*)d_in[9];
    const float* rel_v = (const float*)d_in[10];
    const float* lng_k = (const float*)d_in[11];
    const float* lnb_k = (const float*)d_in[12];
    const float* lng_v = (const float*)d_in[13];
    const float* lnb_v = (const float*)d_in[14];
    float* out = (float*)d_out;

    char* p = (char*)d_ws;
    auto carve = [&](size_t bytes) { char* r = p; p += (bytes + 255) & ~(size_t)255; return r; };
    short* lnkb = (short*)carve((size_t)96 * DD * 2);
    short* lnvT = (short*)carve((size_t)DD * 96 * 2);
    short* hbf  = (short*)carve((size_t)BB * SS * HIDV * 2);
    short* WqT  = (short*)carve((size_t)HIDV * HIDV * 2);
    short* WkT  = (short*)carve((size_t)HIDV * HIDV * 2);
    short* WvT  = (short*)carve((size_t)HIDV * HIDV * 2);
    const size_t per = (size_t)BB * HH * SS * DD;
    short* qbuf = (short*)carve(per * 2);
    short* kbuf = (short*)carve(per * 2);
    short* vtb  = (short*)carve(per * 2);
    unsigned char* arcT8 = (unsigned char*)carve((size_t)BB * SS * SS);

    prep_ln_kernel<<<1, 256, 0, stream>>>(rel_k, rel_v, lng_k, lnb_k, lng_v, lnb_v, lnkb, lnvT);
    conv_hidden_kernel<<<(BB * SS * HIDV) / 1024, 256, 0, stream>>>(hidden, hbf);
    transw_kernel<<<dim3(24, 24, 3), 256, 0, stream>>>(Wq, Wk, Wv, WqT, WkT, WvT);
    arct_kernel<<<dim3(8, 8, BB), 256, 0, stream>>>(arc, arcT8);
    qkv_gemm_kernel<<<dim3(HIDV / 64, (BB * SS) / 64, 3), 256, 0, stream>>>(
        hbf, WqT, WkT, WvT, bq, bk, bv, qbuf, kbuf, vtb);
    attn_kernel<<<dim3(BB * HH * 8), 256, 0, stream>>>(
        qbuf, kbuf, vtb, arcT8, mask, lnkb, lnvT, out);
}

// Round 6
// 199.044 us; speedup vs baseline: 1.0334x; 1.0334x over previous
//
#include <hip/hip_runtime.h>
#include <hip/hip_bf16.h>

#define BB 8
#define SS 512
#define HIDV 768
#define HH 12
#define DD 64
#define LV 81

typedef __attribute__((ext_vector_type(8))) short short8v;
typedef __attribute__((ext_vector_type(4))) short short4v;
typedef __attribute__((ext_vector_type(4))) float f32x4;

#define MFMA16(a, b, c) __builtin_amdgcn_mfma_f32_16x16x32_bf16(a, b, c, 0, 0, 0)

__device__ __forceinline__ short f2bf(float f) {
    __hip_bfloat16 h = __float2bfloat16(f);
    return *reinterpret_cast<short*>(&h);
}
__device__ __forceinline__ float bf2f(short s) {
    __hip_bfloat16 h = *reinterpret_cast<__hip_bfloat16*>(&s);
    return __bfloat162float(h);
}
__device__ __forceinline__ void gload16(const void* g, void* l) {
    __builtin_amdgcn_global_load_lds((const __attribute__((address_space(1))) void*)g,
                                     (__attribute__((address_space(3))) void*)l, 16, 0, 0);
}

// ---------------- Kernel A: LN tables -> lnkb bf16 [96][64], lnvT bf16 [64][96] ----------------
__global__ __launch_bounds__(256) void prep_ln_kernel(
    const float* __restrict__ rel_k, const float* __restrict__ rel_v,
    const float* __restrict__ gk, const float* __restrict__ bk,
    const float* __restrict__ gv, const float* __restrict__ bv,
    short* __restrict__ lnkb, short* __restrict__ lnvT) {
    __shared__ float ln_lds[2 * LV][DD];
    int t = threadIdx.x;
    if (t < 2 * LV) {
        bool isv = (t >= LV);
        int r = isv ? t - LV : t;
        const float* row = (isv ? rel_v : rel_k) + r * DD;
        const float* g = isv ? gv : gk;
        const float* be = isv ? bv : bk;
        float mu = 0.f;
        for (int d = 0; d < DD; ++d) mu += row[d];
        mu *= (1.f / DD);
        float var = 0.f;
        for (int d = 0; d < DD; ++d) { float x = row[d] - mu; var += x * x; }
        var *= (1.f / DD);
        float rs = rsqrtf(var + 1e-5f);
        for (int d = 0; d < DD; ++d) ln_lds[t][d] = (row[d] - mu) * rs * g[d] + be[d];
    }
    __syncthreads();
    for (int i = t; i < 96 * DD; i += 256) {
        int l = i >> 6, d = i & 63;
        lnkb[i] = (l < LV) ? f2bf(ln_lds[l][d]) : (short)0;
    }
    for (int i = t; i < DD * 96; i += 256) {
        int d = i / 96, ll = i - d * 96;
        lnvT[i] = (ll < LV) ? f2bf(ln_lds[LV + ll][d]) : (short)0;
    }
}

// ---------------- hidden f32 -> bf16 ----------------
__global__ __launch_bounds__(256) void conv_hidden_kernel(const float* __restrict__ in,
                                                          short* __restrict__ out) {
    int i = (blockIdx.x * 256 + threadIdx.x) * 4;
    float4 v = *reinterpret_cast<const float4*>(&in[i]);
    short4v o; o[0] = f2bf(v.x); o[1] = f2bf(v.y); o[2] = f2bf(v.z); o[3] = f2bf(v.w);
    *reinterpret_cast<short4v*>(&out[i]) = o;
}

// ---------------- W [k][n] f32 -> WT [n][k] bf16 (x3 via z) ----------------
__global__ __launch_bounds__(256) void transw_kernel(
    const float* __restrict__ Wq, const float* __restrict__ Wk, const float* __restrict__ Wv,
    short* __restrict__ WqT, short* __restrict__ WkT, short* __restrict__ WvT) {
    const float* W; short* O;
    if (blockIdx.z == 0) { W = Wq; O = WqT; }
    else if (blockIdx.z == 1) { W = Wk; O = WkT; }
    else { W = Wv; O = WvT; }
    __shared__ float tile[32][33];
    int k0 = blockIdx.y * 32, n0 = blockIdx.x * 32;
    int t = threadIdx.x;
    int r = t >> 3, c4 = (t & 7) * 4;
    float4 v = *reinterpret_cast<const float4*>(&W[(size_t)(k0 + r) * HIDV + n0 + c4]);
    tile[r][c4 + 0] = v.x; tile[r][c4 + 1] = v.y; tile[r][c4 + 2] = v.z; tile[r][c4 + 3] = v.w;
    __syncthreads();
    short4v o;
    o[0] = f2bf(tile[c4 + 0][r]); o[1] = f2bf(tile[c4 + 1][r]);
    o[2] = f2bf(tile[c4 + 2][r]); o[3] = f2bf(tile[c4 + 3][r]);
    *reinterpret_cast<short4v*>(&O[(size_t)(n0 + r) * HIDV + k0 + c4]) = o;
}

// ---------------- arc int32 [b][q][k] -> packed u32 arcP [b][k>>2][q] (4 labels/u32) ----------------
__global__ __launch_bounds__(256) void arcpack_kernel(const int* __restrict__ arc,
                                                      unsigned int* __restrict__ arcP) {
    __shared__ unsigned int tbuf[64][129];
    const int tid = threadIdx.x;
    const int b = blockIdx.y;
    const int q0 = blockIdx.x * 64;
    for (int i = tid; i < 64 * 128; i += 256) {
        int r = i >> 7, c4 = i & 127;
        int4 v = *reinterpret_cast<const int4*>(&arc[((size_t)(b * SS) + q0 + r) * SS + 4 * c4]);
        tbuf[r][c4] = (unsigned)(v.x & 255) | ((unsigned)(v.y & 255) << 8) |
                      ((unsigned)(v.z & 255) << 16) | ((unsigned)(v.w & 255) << 24);
    }
    __syncthreads();
    for (int i = tid; i < 128 * 64; i += 256) {
        int k4 = i >> 6, r = i & 63;
        arcP[((size_t)b * 128 + k4) * SS + q0 + r] = tbuf[r][k4];
    }
}

// ---------------- QKV GEMM bf16 MFMA (unchanged) ----------------
__global__ __launch_bounds__(256) void qkv_gemm_kernel(
    const short* __restrict__ Abf,
    const short* __restrict__ WqT, const short* __restrict__ WkT, const short* __restrict__ WvT,
    const float* __restrict__ bq, const float* __restrict__ bk, const float* __restrict__ bv,
    short* __restrict__ qo, short* __restrict__ ko, short* __restrict__ vto) {
    const short* Bt; const float* bias;
    int z = blockIdx.z;
    if (z == 0) { Bt = WqT; bias = bq; }
    else if (z == 1) { Bt = WkT; bias = bk; }
    else { Bt = WvT; bias = bv; }

    __shared__ short smem[8192];
    short* As = smem;
    short* Bs = smem + 4096;

    const int tid = threadIdx.x;
    const int lane = tid & 63, w = tid >> 6;
    const int li = lane & 15, g = lane >> 4;
    const int wr = w >> 1, wc = w & 1;
    const int m0 = blockIdx.y * 64, n0 = blockIdx.x * 64;

    f32x4 acc[2][2];
    for (int ra = 0; ra < 2; ++ra)
        for (int cb = 0; cb < 2; ++cb)
            for (int r = 0; r < 4; ++r) acc[ra][cb][r] = 0.f;

#pragma unroll 1
    for (int k0 = 0; k0 < HIDV; k0 += 64) {
#pragma unroll
        for (int j = 0; j < 2; ++j) {
            int c = j * 256 + tid;
            int row = c >> 3, s = c & 7;
            int src = s ^ (row & 7);
            gload16(Abf + (size_t)(m0 + row) * HIDV + k0 + src * 8, As + c * 8);
            gload16(Bt + (size_t)(n0 + row) * HIDV + k0 + src * 8, Bs + c * 8);
        }
        __syncthreads();
#pragma unroll
        for (int c = 0; c < 2; ++c) {
            short8v af[2], bf[2];
#pragma unroll
            for (int ra = 0; ra < 2; ++ra) {
                int row = 32 * wr + 16 * ra + li;
                int chunk = (4 * c + g) ^ (row & 7);
                af[ra] = *reinterpret_cast<const short8v*>(&As[row * 64 + chunk * 8]);
            }
#pragma unroll
            for (int cb = 0; cb < 2; ++cb) {
                int rowb = 32 * wc + 16 * cb + li;
                int chunk = (4 * c + g) ^ (rowb & 7);
                bf[cb] = *reinterpret_cast<const short8v*>(&Bs[rowb * 64 + chunk * 8]);
            }
#pragma unroll
            for (int ra = 0; ra < 2; ++ra)
#pragma unroll
                for (int cb = 0; cb < 2; ++cb)
                    acc[ra][cb] = MFMA16(af[ra], bf[cb], acc[ra][cb]);
        }
        __syncthreads();
    }

    const int h = n0 >> 6;
    const int bidx = m0 >> 9;
    if (z < 2) {
        short* dst = (z == 0) ? qo : ko;
        float sc = (z == 0) ? 1.f : 0.125f;
#pragma unroll
        for (int ra = 0; ra < 2; ++ra)
#pragma unroll
            for (int cb = 0; cb < 2; ++cb) {
                int n = 32 * wc + 16 * cb + li;
                float bv_ = bias[n0 + n];
#pragma unroll
                for (int r = 0; r < 4; ++r) {
                    int m = m0 + 32 * wr + 16 * ra + 4 * g + r;
                    int s = m & 511;
                    dst[(((size_t)bidx * HH + h) * SS + s) * DD + n] =
                        f2bf((acc[ra][cb][r] + bv_) * sc);
                }
            }
    } else {
        short* Cs = smem;
#pragma unroll
        for (int ra = 0; ra < 2; ++ra)
#pragma unroll
            for (int cb = 0; cb < 2; ++cb) {
                int nl = 32 * wc + 16 * cb + li;
                float bv_ = bias[n0 + nl];
#pragma unroll
                for (int r = 0; r < 4; ++r) {
                    int ml = 32 * wr + 16 * ra + 4 * g + r;
                    Cs[nl * 72 + ml] = f2bf(acc[ra][cb][r] + bv_);
                }
            }
        __syncthreads();
        for (int c = tid; c < 512; c += 256) {
            int dl = c >> 3, s8 = (c & 7) * 8;
            short8v vv = *reinterpret_cast<const short8v*>(&Cs[dl * 72 + s8]);
            *reinterpret_cast<short8v*>(
                &vto[(((size_t)bidx * HH + h) * DD + dl) * SS + (m0 & 511) + s8]) = vv;
        }
    }
}

// ---------------- fused MFMA attention: barrier-free, swapped-QK, in-register P ----------------
// 256 thr = 4 waves, each wave fully independent: 16 q-rows of one bh.
// Swapped QK (S^T = K·Q^T): lane owns P[q=li][k=16t+4g+r]. PV uses the verified
// 16x16x32 MFMA with a custom slot->k permutation matching the lane's owned k,
// so P never leaves registers. arc is pre-packed 4-labels/u32 (coalesced).
// Only LDS: qrel gather table + label buckets (wave-private). Zero barriers.
__global__ __launch_bounds__(256, 3) void attn_kernel(
    const short* __restrict__ qb, const short* __restrict__ kb, const short* __restrict__ vt,
    const unsigned int* __restrict__ arcP, const float* __restrict__ maskp,
    const short* __restrict__ lnkb, const short* __restrict__ lnvT,
    float* __restrict__ outp) {
    __shared__ float qlds[4][16][84];    // 21 KB: qrel[q-row][label], wave-private
    __shared__ float bucket[4][16][96];  // 24 KB: label buckets, wave-private (cols 81..95 = 0)

    const int tid = threadIdx.x;
    const int w = tid >> 6, lane = tid & 63;
    const int li = lane & 15, g = lane >> 4;
    const int bx = blockIdx.x;
    const int b = bx & 7;                 // XCD affinity: batch-major
    const int rest = bx >> 3;
    const int h = rest % HH, qt = rest / HH;   // qt 0..7
    const int bh = b * HH + h;
    const int q0 = qt * 64 + w * 16;

    const short* kbp = kb + (size_t)bh * SS * DD;
    const short* vbp = vt + (size_t)bh * DD * SS;

    // zero buckets (wave-private)
    for (int i = lane; i < 16 * 96; i += 64) (&bucket[w][0][0])[i] = 0.f;

    // Q fragments (B-operand: lane li = Q[q0+li][d-slots])
    short8v qf[2];
    {
        const short* qrow = qb + ((size_t)bh * SS + q0 + li) * DD + 8 * g;
        qf[0] = *reinterpret_cast<const short8v*>(qrow);
        qf[1] = *reinterpret_cast<const short8v*>(qrow + 32);
    }

    // qrel tile via MFMA: qlds[q-row][label] = Q(16x64) @ lnkb^T (wave-private)
    {
        f32x4 qr[6];
#pragma unroll
        for (int ct = 0; ct < 6; ++ct) {
            f32x4 a = {0.f, 0.f, 0.f, 0.f};
            short8v b0 = *reinterpret_cast<const short8v*>(&lnkb[(16 * ct + li) * DD + 8 * g]);
            short8v b1 = *reinterpret_cast<const short8v*>(&lnkb[(16 * ct + li) * DD + 32 + 8 * g]);
            a = MFMA16(qf[0], b0, a);
            a = MFMA16(qf[1], b1, a);
            qr[ct] = a;
        }
#pragma unroll
        for (int ct = 0; ct < 6; ++ct)
#pragma unroll
            for (int r = 0; r < 4; ++r)
                if (16 * ct + li < 84) qlds[w][4 * g + r][16 * ct + li] = qr[ct][r];
    }

    f32x4 oacc[4];
    for (int t = 0; t < 4; ++t) for (int r = 0; r < 4; ++r) oacc[t][r] = 0.f;
    float lsum = 0.f;   // row-sum for q = li (this lane's column)

#pragma unroll 2
    for (int kt = 0; kt < 8; ++kt) {
        const int kb0 = kt * 64;

        // packed arc labels: byte r of a4[t] = arc label for (q=q0+li, k=kb0+16t+4g+r)
        unsigned int a4[4];
#pragma unroll
        for (int t = 0; t < 4; ++t)
            a4[t] = arcP[((size_t)b * 128 + kt * 16 + 4 * t + g) * SS + q0 + li];

        // mask: component r = mask[b][kb0+16t+4g+r]  (broadcast within 16-lane groups)
        float4 mv[4];
#pragma unroll
        for (int t = 0; t < 4; ++t)
            mv[t] = *reinterpret_cast<const float4*>(&maskp[(size_t)b * SS + kb0 + 16 * t + 4 * g]);

        // swapped QK: sacc[t] = K-tile(16 rows) . Q^T -> C[k=16t+4g+r][q=li]
        f32x4 sacc[4];
#pragma unroll
        for (int t = 0; t < 4; ++t) {
            const short* kr = kbp + (size_t)(kb0 + 16 * t + li) * DD + 8 * g;
            short8v k0 = *reinterpret_cast<const short8v*>(kr);
            short8v k1 = *reinterpret_cast<const short8v*>(kr + 32);
            f32x4 a = {0.f, 0.f, 0.f, 0.f};
            a = MFMA16(k0, qf[0], a);
            a = MFMA16(k1, qf[1], a);
            sacc[t] = a;
        }

        // exp (no max; scores bounded), bucket atomic, pack P into PV A-frags.
        // pfrag[dt] slot j holds P[q=li][k = kb0+32dt+16*(j>>2)+4g+(j&3)]
        short8v pfrag[2];
#pragma unroll
        for (int t = 0; t < 4; ++t) {
            float pv[4];
#pragma unroll
            for (int r = 0; r < 4; ++r) {
                const int a_ = (a4[t] >> (8 * r)) & 255;
                float s = sacc[t][r] + qlds[w][li][a_] +
                          reinterpret_cast<const float*>(&mv[t])[r];
                float p = __expf(s);
                lsum += p;
                atomicAdd(&bucket[w][li][a_], p);
                pv[r] = p;
            }
#pragma unroll
            for (int r = 0; r < 4; ++r) pfrag[t >> 1][4 * (t & 1) + r] = f2bf(pv[r]);
        }

        // PV with matching slot permutation: vf slot j = V[k(slot)][d=16t2+li]
#pragma unroll
        for (int dt = 0; dt < 2; ++dt) {
#pragma unroll
            for (int t2 = 0; t2 < 4; ++t2) {
                const short* vr = vbp + (size_t)(16 * t2 + li) * SS + kb0 + 32 * dt + 4 * g;
                short4v v0 = *reinterpret_cast<const short4v*>(vr);
                short4v v1 = *reinterpret_cast<const short4v*>(vr + 16);
                short8v vf;
                vf[0] = v0[0]; vf[1] = v0[1]; vf[2] = v0[2]; vf[3] = v0[3];
                vf[4] = v1[0]; vf[5] = v1[1]; vf[6] = v1[2]; vf[7] = v1[3];
                oacc[t2] = MFMA16(pfrag[dt], vf, oacc[t2]);
            }
        }
    }

    // lsum lives per q=li in 4 lanes (g=0..3): reduce across g
    lsum += __shfl_xor(lsum, 16);
    lsum += __shfl_xor(lsum, 32);
    float inv = 1.f / lsum;
    // output rows are q = 4g+r: fetch inv from lane (4g+r)
    float invr[4];
#pragma unroll
    for (int r = 0; r < 4; ++r) invr[r] = __shfl(inv, 4 * g + r);

    // rel-V: racc = bucket @ lnvT  (A rows = q = li; labels zero-padded to 96)
    f32x4 racc[4];
    for (int t = 0; t < 4; ++t) for (int r = 0; r < 4; ++r) racc[t][r] = 0.f;
#pragma unroll
    for (int c = 0; c < 3; ++c) {
        f32x4 b0 = *reinterpret_cast<const f32x4*>(&bucket[w][li][8 * g + 32 * c]);
        f32x4 b1 = *reinterpret_cast<const f32x4*>(&bucket[w][li][8 * g + 32 * c + 4]);
        short8v bfr;
        bfr[0] = f2bf(b0[0]); bfr[1] = f2bf(b0[1]); bfr[2] = f2bf(b0[2]); bfr[3] = f2bf(b0[3]);
        bfr[4] = f2bf(b1[0]); bfr[5] = f2bf(b1[1]); bfr[6] = f2bf(b1[2]); bfr[7] = f2bf(b1[3]);
#pragma unroll
        for (int t2 = 0; t2 < 4; ++t2) {
            short8v lf = *reinterpret_cast<const short8v*>(
                &lnvT[(16 * t2 + li) * 96 + 8 * g + 32 * c]);
            racc[t2] = MFMA16(bfr, lf, racc[t2]);
        }
    }

    // write: C[q=4g+r][d=16t2+li]
#pragma unroll
    for (int t2 = 0; t2 < 4; ++t2)
#pragma unroll
        for (int r = 0; r < 4; ++r) {
            int row = q0 + 4 * g + r;
            outp[((size_t)b * SS + row) * HIDV + h * DD + 16 * t2 + li] =
                (oacc[t2][r] + racc[t2][r]) * invr[r];
        }
}

// ---------------- launcher ----------------
extern "C" void kernel_launch(void* const* d_in, const int* in_sizes, int n_in,
                              void* d_out, int out_size, void* d_ws, size_t ws_size,
                              hipStream_t stream) {
    const float* hidden = (const float*)d_in[0];
    const float* mask   = (const float*)d_in[1];
    const int*   arc    = (const int*)d_in[2];
    const float* Wq = (const float*)d_in[3];
    const float* bq = (const float*)d_in[4];
    const float* Wk = (const float*)d_in[5];
    const float* bk = (const float*)d_in[6];
    const float* Wv = (const float*)d_in[7];
    const float* bv = (const float*)d_in[8];
    const float* rel_k = (const float*)d_in[9];
    const float* rel_v = (const float*)d_in[10];
    const float* lng_k = (const float*)d_in[11];
    const float* lnb_k = (const float*)d_in[12];
    const float* lng_v = (const float*)d_in[13];
    const float* lnb_v = (const float*)d_in[14];
    float* out = (float*)d_out;

    char* p = (char*)d_ws;
    auto carve = [&](size_t bytes) { char* r = p; p += (bytes + 255) & ~(size_t)255; return r; };
    short* lnkb = (short*)carve((size_t)96 * DD * 2);
    short* lnvT = (short*)carve((size_t)DD * 96 * 2);
    short* hbf  = (short*)carve((size_t)BB * SS * HIDV * 2);
    short* WqT  = (short*)carve((size_t)HIDV * HIDV * 2);
    short* WkT  = (short*)carve((size_t)HIDV * HIDV * 2);
    short* WvT  = (short*)carve((size_t)HIDV * HIDV * 2);
    const size_t per = (size_t)BB * HH * SS * DD;
    short* qbuf = (short*)carve(per * 2);
    short* kbuf = (short*)carve(per * 2);
    short* vtb  = (short*)carve(per * 2);
    unsigned int* arcP = (unsigned int*)carve((size_t)BB * 128 * SS * 4);

    prep_ln_kernel<<<1, 256, 0, stream>>>(rel_k, rel_v, lng_k, lnb_k, lng_v, lnb_v, lnkb, lnvT);
    conv_hidden_kernel<<<(BB * SS * HIDV) / 1024, 256, 0, stream>>>(hidden, hbf);
    transw_kernel<<<dim3(24, 24, 3), 256, 0, stream>>>(Wq, Wk, Wv, WqT, WkT, WvT);
    arcpack_kernel<<<dim3(8, BB), 256, 0, stream>>>(arc, arcP);
    qkv_gemm_kernel<<<dim3(HIDV / 64, (BB * SS) / 64, 3), 256, 0, stream>>>(
        hbf, WqT, WkT, WvT, bq, bk, bv, qbuf, kbuf, vtb);
    attn_kernel<<<dim3(BB * HH * 8), 256, 0, stream>>>(
        qbuf, kbuf, vtb, arcP, mask, lnkb, lnvT, out);
}